// Round 2
// baseline (1311.803 us; speedup 1.0000x reference)
//
#include <hip/hip_runtime.h>

#define CLAMP_MIN_F (-10.0f)
#define CLAMP_MAX_F (10.0f)
#define BATCH 8

// Transpose (B,N) row-major -> (N,B). One thread per node n, loop over b.
// Reads coalesced along n for each b; writes 32B blocks, consecutive per thread.
__global__ void transpose_BN_to_NB(const float* __restrict__ in,
                                   float* __restrict__ out,
                                   int N) {
    int n = blockIdx.x * blockDim.x + threadIdx.x;
    if (n >= N) return;
    float v[BATCH];
    #pragma unroll
    for (int b = 0; b < BATCH; ++b) v[b] = in[b * N + n];
    float4* o = (float4*)&out[n * BATCH];
    o[0] = make_float4(v[0], v[1], v[2], v[3]);
    o[1] = make_float4(v[4], v[5], v[6], v[7]);
}

// Edge scatter: one thread per edge. All per-edge table accesses are within
// single 32B node records -> 1-2 cachelines per table per edge.
__global__ void edge_scatter_nb(const int* __restrict__ src,
                                const int* __restrict__ dst,
                                const float* __restrict__ w,
                                const float* __restrict__ o_preT,  // (N,B)
                                const float* __restrict__ E_T,     // (N,B)
                                float* __restrict__ chemT,         // (N,B)
                                int edges) {
    int e = blockIdx.x * blockDim.x + threadIdx.x;
    if (e >= edges) return;
    int s = src[e];
    int d = dst[e];
    float we = w[e];

    const float4* op = (const float4*)&o_preT[s * BATCH];
    const float4* ep = (const float4*)&E_T[d * BATCH];
    float4 o0 = op[0], o1 = op[1];
    float4 e0 = ep[0], e1 = ep[1];

    float Oj[BATCH] = {o0.x, o0.y, o0.z, o0.w, o1.x, o1.y, o1.z, o1.w};
    float En[BATCH] = {e0.x, e0.y, e0.z, e0.w, e1.x, e1.y, e1.z, e1.w};

    float* cp = &chemT[d * BATCH];
    #pragma unroll
    for (int b = 0; b < BATCH; ++b) {
        float diff = Oj[b] - En[b];
        float sg = (diff > 0.0f) ? 1.0f : ((diff < 0.0f) ? -1.0f : 0.0f);
        float contrib = Oj[b] * we * sg;
        atomicAdd(&cp[b], contrib);
    }
}

// Finalize: one thread per node n, loop over b. Reads chemT (N,B) records,
// E (B,N) coalesced; writes outputs (B,N) coalesced.
__global__ void finalize_nb(const float* __restrict__ E,      // (B,N)
                            const float* __restrict__ chemT,  // (N,B)
                            const float* __restrict__ thr,
                            const float* __restrict__ decay,
                            float* __restrict__ new_o,        // (B,N)
                            float* __restrict__ new_e,        // (B,N)
                            int N) {
    int n = blockIdx.x * blockDim.x + threadIdx.x;
    if (n >= N) return;
    const float4* cp = (const float4*)&chemT[n * BATCH];
    float4 c0 = cp[0], c1 = cp[1];
    float c[BATCH] = {c0.x, c0.y, c0.z, c0.w, c1.x, c1.y, c1.z, c1.w};
    float t = thr[n];
    float dc = decay[n];
    #pragma unroll
    for (int b = 0; b < BATCH; ++b) {
        int i = b * N + n;
        float e = E[i];
        float S = e + c[b];
        S = fminf(fmaxf(S, CLAMP_MIN_F), CLAMP_MAX_F);
        bool gt = S > t;
        float no = fmaxf(S - t, 0.0f);
        float ne;
        if (gt)           ne = no;
        else if (S == e)  ne = e - dc;
        else              ne = S;
        new_o[i] = no;
        new_e[i] = ne;
    }
}

// ---- Fallback path (B,N layout, from round 1) in case ws is too small ----
__global__ void init_chem_kernel(const float* __restrict__ chem_in,
                                 float* __restrict__ chem, int total) {
    int i = blockIdx.x * blockDim.x + threadIdx.x;
    if (i < total) chem[i] = chem_in[i];
}
__global__ void edge_scatter_kernel(const int* __restrict__ src,
                                    const int* __restrict__ dst,
                                    const float* __restrict__ w,
                                    const float* __restrict__ o_pre,
                                    const float* __restrict__ E,
                                    float* __restrict__ chem,
                                    int edges, int N) {
    int e = blockIdx.x * blockDim.x + threadIdx.x;
    if (e >= edges) return;
    int s = src[e]; int d = dst[e]; float we = w[e];
    #pragma unroll
    for (int b = 0; b < BATCH; ++b) {
        int base = b * N;
        float Oj = o_pre[base + s];
        float En = E[base + d];
        float diff = Oj - En;
        float sg = (diff > 0.0f) ? 1.0f : ((diff < 0.0f) ? -1.0f : 0.0f);
        atomicAdd(&chem[base + d], Oj * we * sg);
    }
}
__global__ void finalize_kernel(const float* __restrict__ E,
                                const float* __restrict__ chem,
                                const float* __restrict__ thr,
                                const float* __restrict__ decay,
                                float* __restrict__ new_o,
                                float* __restrict__ new_e,
                                int N, int total) {
    int i = blockIdx.x * blockDim.x + threadIdx.x;
    if (i >= total) return;
    int n = i % N;
    float e = E[i];
    float S = fminf(fmaxf(e + chem[i], CLAMP_MIN_F), CLAMP_MAX_F);
    float t = thr[n];
    bool gt = S > t;
    float no = fmaxf(S - t, 0.0f);
    float ne = gt ? no : ((S == e) ? (e - decay[n]) : S);
    new_o[i] = no;
    new_e[i] = ne;
}

extern "C" void kernel_launch(void* const* d_in, const int* in_sizes, int n_in,
                              void* d_out, int out_size, void* d_ws, size_t ws_size,
                              hipStream_t stream) {
    const float* chem_influence = (const float*)d_in[0];
    const float* E              = (const float*)d_in[1];
    const int*   src            = (const int*)d_in[3];
    const int*   dst            = (const int*)d_in[4];
    const float* w              = (const float*)d_in[5];
    const float* o_pre          = (const float*)d_in[6];
    const float* threshold      = (const float*)d_in[7];
    const float* decay          = (const float*)d_in[8];

    const int edges = in_sizes[3];
    const int BN    = in_sizes[0];   // B * N
    const int N     = in_sizes[7];   // threshold is (N,)

    float* new_o = (float*)d_out;
    float* new_e = (float*)d_out + BN;

    const int TB = 256;
    const size_t tableBytes = (size_t)BN * sizeof(float);

    if (ws_size >= 3 * tableBytes) {
        float* chemT  = (float*)d_ws;                 // (N,B)
        float* o_preT = chemT + BN;                   // (N,B)
        float* E_T    = o_preT + BN;                  // (N,B)

        int nblk = (N + TB - 1) / TB;
        transpose_BN_to_NB<<<nblk, TB, 0, stream>>>(chem_influence, chemT, N);
        transpose_BN_to_NB<<<nblk, TB, 0, stream>>>(o_pre, o_preT, N);
        transpose_BN_to_NB<<<nblk, TB, 0, stream>>>(E, E_T, N);

        edge_scatter_nb<<<(edges + TB - 1) / TB, TB, 0, stream>>>(
            src, dst, w, o_preT, E_T, chemT, edges);

        finalize_nb<<<nblk, TB, 0, stream>>>(E, chemT, threshold, decay,
                                             new_o, new_e, N);
    } else {
        // Fallback: original (B,N) path
        float* chem = (float*)d_ws;
        init_chem_kernel<<<(BN + TB - 1) / TB, TB, 0, stream>>>(chem_influence, chem, BN);
        edge_scatter_kernel<<<(edges + TB - 1) / TB, TB, 0, stream>>>(
            src, dst, w, o_pre, E, chem, edges, N);
        finalize_kernel<<<(BN + TB - 1) / TB, TB, 0, stream>>>(
            E, chem, threshold, decay, new_o, new_e, N, BN);
    }
}

// Round 3
// 182.471 us; speedup vs baseline: 7.1891x; 7.1891x over previous
//
#include <hip/hip_runtime.h>

#define CLAMP_MIN_F (-10.0f)
#define CLAMP_MAX_F (10.0f)
#define BATCH 8

// Transpose (B,N) row-major -> (N,B). One thread per node n, loop over b.
__global__ void transpose_BN_to_NB(const float* __restrict__ in,
                                   float* __restrict__ out,
                                   int N) {
    int n = blockIdx.x * blockDim.x + threadIdx.x;
    if (n >= N) return;
    float v[BATCH];
    #pragma unroll
    for (int b = 0; b < BATCH; ++b) v[b] = in[b * N + n];
    float4* o = (float4*)&out[n * BATCH];
    o[0] = make_float4(v[0], v[1], v[2], v[3]);
    o[1] = make_float4(v[4], v[5], v[6], v[7]);
}

// Edge scatter: one thread per (edge, batch). Lanes 0..7 of each 8-lane group
// share one edge; their atomics hit 8 CONSECUTIVE floats (one 32B line), so a
// single global_atomic_add_f32 instruction per wave covers 8 edges x 8 batches
// with only 8 distinct lines -> per-instruction coalescing of same-line atomics.
__global__ void edge_scatter_eb(const int* __restrict__ src,
                                const int* __restrict__ dst,
                                const float* __restrict__ w,
                                const float* __restrict__ o_preT,  // (N,B)
                                const float* __restrict__ E_T,     // (N,B)
                                float* __restrict__ chemT,         // (N,B)
                                int edges) {
    int t = blockIdx.x * blockDim.x + threadIdx.x;
    int e = t >> 3;
    int b = t & 7;
    if (e >= edges) return;
    int s = src[e];        // 8 lanes read same address -> broadcast
    int d = dst[e];
    float we = w[e];
    float Oj = o_preT[s * BATCH + b];   // 8-lane group reads one 32B record
    float En = E_T[d * BATCH + b];
    float diff = Oj - En;
    float sg = (diff > 0.0f) ? 1.0f : ((diff < 0.0f) ? -1.0f : 0.0f);
    float contrib = Oj * we * sg;
    atomicAdd(&chemT[d * BATCH + b], contrib);
}

// Finalize: one thread per node n, loop over b.
__global__ void finalize_nb(const float* __restrict__ E,      // (B,N)
                            const float* __restrict__ chemT,  // (N,B)
                            const float* __restrict__ thr,
                            const float* __restrict__ decay,
                            float* __restrict__ new_o,        // (B,N)
                            float* __restrict__ new_e,        // (B,N)
                            int N) {
    int n = blockIdx.x * blockDim.x + threadIdx.x;
    if (n >= N) return;
    const float4* cp = (const float4*)&chemT[n * BATCH];
    float4 c0 = cp[0], c1 = cp[1];
    float c[BATCH] = {c0.x, c0.y, c0.z, c0.w, c1.x, c1.y, c1.z, c1.w};
    float t = thr[n];
    float dc = decay[n];
    #pragma unroll
    for (int b = 0; b < BATCH; ++b) {
        int i = b * N + n;
        float e = E[i];
        float S = e + c[b];
        S = fminf(fmaxf(S, CLAMP_MIN_F), CLAMP_MAX_F);
        bool gt = S > t;
        float no = fmaxf(S - t, 0.0f);
        float ne;
        if (gt)           ne = no;
        else if (S == e)  ne = e - dc;
        else              ne = S;
        new_o[i] = no;
        new_e[i] = ne;
    }
}

// ---- Fallback path (B,N layout) in case ws is too small ----
__global__ void init_chem_kernel(const float* __restrict__ chem_in,
                                 float* __restrict__ chem, int total) {
    int i = blockIdx.x * blockDim.x + threadIdx.x;
    if (i < total) chem[i] = chem_in[i];
}
__global__ void edge_scatter_kernel(const int* __restrict__ src,
                                    const int* __restrict__ dst,
                                    const float* __restrict__ w,
                                    const float* __restrict__ o_pre,
                                    const float* __restrict__ E,
                                    float* __restrict__ chem,
                                    int edges, int N) {
    int e = blockIdx.x * blockDim.x + threadIdx.x;
    if (e >= edges) return;
    int s = src[e]; int d = dst[e]; float we = w[e];
    #pragma unroll
    for (int b = 0; b < BATCH; ++b) {
        int base = b * N;
        float Oj = o_pre[base + s];
        float En = E[base + d];
        float diff = Oj - En;
        float sg = (diff > 0.0f) ? 1.0f : ((diff < 0.0f) ? -1.0f : 0.0f);
        atomicAdd(&chem[base + d], Oj * we * sg);
    }
}
__global__ void finalize_kernel(const float* __restrict__ E,
                                const float* __restrict__ chem,
                                const float* __restrict__ thr,
                                const float* __restrict__ decay,
                                float* __restrict__ new_o,
                                float* __restrict__ new_e,
                                int N, int total) {
    int i = blockIdx.x * blockDim.x + threadIdx.x;
    if (i >= total) return;
    int n = i % N;
    float e = E[i];
    float S = fminf(fmaxf(e + chem[i], CLAMP_MIN_F), CLAMP_MAX_F);
    float t = thr[n];
    bool gt = S > t;
    float no = fmaxf(S - t, 0.0f);
    float ne = gt ? no : ((S == e) ? (e - decay[n]) : S);
    new_o[i] = no;
    new_e[i] = ne;
}

extern "C" void kernel_launch(void* const* d_in, const int* in_sizes, int n_in,
                              void* d_out, int out_size, void* d_ws, size_t ws_size,
                              hipStream_t stream) {
    const float* chem_influence = (const float*)d_in[0];
    const float* E              = (const float*)d_in[1];
    const int*   src            = (const int*)d_in[3];
    const int*   dst            = (const int*)d_in[4];
    const float* w              = (const float*)d_in[5];
    const float* o_pre          = (const float*)d_in[6];
    const float* threshold      = (const float*)d_in[7];
    const float* decay          = (const float*)d_in[8];

    const int edges = in_sizes[3];
    const int BN    = in_sizes[0];   // B * N
    const int N     = in_sizes[7];   // threshold is (N,)

    float* new_o = (float*)d_out;
    float* new_e = (float*)d_out + BN;

    const int TB = 256;
    const size_t tableBytes = (size_t)BN * sizeof(float);

    if (ws_size >= 3 * tableBytes) {
        float* chemT  = (float*)d_ws;                 // (N,B)
        float* o_preT = chemT + BN;                   // (N,B)
        float* E_T    = o_preT + BN;                  // (N,B)

        int nblk = (N + TB - 1) / TB;
        transpose_BN_to_NB<<<nblk, TB, 0, stream>>>(chem_influence, chemT, N);
        transpose_BN_to_NB<<<nblk, TB, 0, stream>>>(o_pre, o_preT, N);
        transpose_BN_to_NB<<<nblk, TB, 0, stream>>>(E, E_T, N);

        long long threads = (long long)edges * BATCH;
        int gblk = (int)((threads + TB - 1) / TB);
        edge_scatter_eb<<<gblk, TB, 0, stream>>>(
            src, dst, w, o_preT, E_T, chemT, edges);

        finalize_nb<<<nblk, TB, 0, stream>>>(E, chemT, threshold, decay,
                                             new_o, new_e, N);
    } else {
        float* chem = (float*)d_ws;
        init_chem_kernel<<<(BN + TB - 1) / TB, TB, 0, stream>>>(chem_influence, chem, BN);
        edge_scatter_kernel<<<(edges + TB - 1) / TB, TB, 0, stream>>>(
            src, dst, w, o_pre, E, chem, edges, N);
        finalize_kernel<<<(BN + TB - 1) / TB, TB, 0, stream>>>(
            E, chem, threshold, decay, new_o, new_e, N, BN);
    }
}

// Round 4
// 181.205 us; speedup vs baseline: 7.2393x; 1.0070x over previous
//
#include <hip/hip_runtime.h>

#define CLAMP_MIN_F (-10.0f)
#define CLAMP_MAX_F (10.0f)
#define BATCH 8
#define NREP 8   // one chem replica per XCD

// Prep: transpose chem_influence/o_pre/E from (B,N) to (N,B) records, and
// zero-fill chem replicas 1..7 (replica 0 = transposed chem_influence).
__global__ void prep_kernel(const float* __restrict__ chem_in,
                            const float* __restrict__ o_pre,
                            const float* __restrict__ E,
                            float* __restrict__ chemRep,   // (NREP, N, B)
                            float* __restrict__ o_preT,    // (N,B)
                            float* __restrict__ E_T,       // (N,B)
                            int N, int BN) {
    int n = blockIdx.x * blockDim.x + threadIdx.x;
    if (n >= N) return;
    float c[BATCH], o[BATCH], ee[BATCH];
    #pragma unroll
    for (int b = 0; b < BATCH; ++b) {
        c[b]  = chem_in[b * N + n];
        o[b]  = o_pre[b * N + n];
        ee[b] = E[b * N + n];
    }
    float4* cp = (float4*)&chemRep[(size_t)n * BATCH];
    cp[0] = make_float4(c[0], c[1], c[2], c[3]);
    cp[1] = make_float4(c[4], c[5], c[6], c[7]);
    float4* op = (float4*)&o_preT[(size_t)n * BATCH];
    op[0] = make_float4(o[0], o[1], o[2], o[3]);
    op[1] = make_float4(o[4], o[5], o[6], o[7]);
    float4* ep = (float4*)&E_T[(size_t)n * BATCH];
    ep[0] = make_float4(ee[0], ee[1], ee[2], ee[3]);
    ep[1] = make_float4(ee[4], ee[5], ee[6], ee[7]);
    float4 z = make_float4(0.f, 0.f, 0.f, 0.f);
    #pragma unroll
    for (int r = 1; r < NREP; ++r) {
        float4* rp = (float4*)&chemRep[(size_t)r * BN + (size_t)n * BATCH];
        rp[0] = z; rp[1] = z;
    }
}

// Edge scatter with per-XCD replicas. Thread = (edge, batch). The 8 lanes of
// an edge-group issue atomics to 8 consecutive floats (one 32B segment), and
// the atomic targets this XCD's private replica -> workgroup-scope atomic
// executes in the local L2 instead of at the memory side.
__global__ void edge_scatter_rep(const int* __restrict__ src,
                                 const int* __restrict__ dst,
                                 const float* __restrict__ w,
                                 const float* __restrict__ o_preT,  // (N,B)
                                 const float* __restrict__ E_T,     // (N,B)
                                 float* __restrict__ chemRep,       // (NREP,N,B)
                                 int edges, int BN) {
    int t = blockIdx.x * blockDim.x + threadIdx.x;
    int e = t >> 3;
    int b = t & 7;
    if (e >= edges) return;
    int xcc;
    asm volatile("s_getreg_b32 %0, hwreg(HW_REG_XCC_ID)" : "=s"(xcc));
    int s = src[e];
    int d = dst[e];
    float we = w[e];
    float Oj = o_preT[(size_t)s * BATCH + b];
    float En = E_T[(size_t)d * BATCH + b];
    float diff = Oj - En;
    float sg = (diff > 0.0f) ? 1.0f : ((diff < 0.0f) ? -1.0f : 0.0f);
    float contrib = Oj * we * sg;
    __hip_atomic_fetch_add(&chemRep[(size_t)xcc * BN + (size_t)d * BATCH + b],
                           contrib, __ATOMIC_RELAXED, __HIP_MEMORY_SCOPE_WORKGROUP);
}

// Finalize: sum the NREP replicas per node, then elementwise epilogue.
__global__ void finalize_rep(const float* __restrict__ E,        // (B,N)
                             const float* __restrict__ chemRep,  // (NREP,N,B)
                             const float* __restrict__ thr,
                             const float* __restrict__ decay,
                             float* __restrict__ new_o,          // (B,N)
                             float* __restrict__ new_e,          // (B,N)
                             int N, int BN) {
    int n = blockIdx.x * blockDim.x + threadIdx.x;
    if (n >= N) return;
    float c[BATCH];
    {
        const float4* cp = (const float4*)&chemRep[(size_t)n * BATCH];
        float4 c0 = cp[0], c1 = cp[1];
        c[0]=c0.x; c[1]=c0.y; c[2]=c0.z; c[3]=c0.w;
        c[4]=c1.x; c[5]=c1.y; c[6]=c1.z; c[7]=c1.w;
    }
    #pragma unroll
    for (int r = 1; r < NREP; ++r) {
        const float4* cp = (const float4*)&chemRep[(size_t)r * BN + (size_t)n * BATCH];
        float4 c0 = cp[0], c1 = cp[1];
        c[0]+=c0.x; c[1]+=c0.y; c[2]+=c0.z; c[3]+=c0.w;
        c[4]+=c1.x; c[5]+=c1.y; c[6]+=c1.z; c[7]+=c1.w;
    }
    float t = thr[n];
    float dc = decay[n];
    #pragma unroll
    for (int b = 0; b < BATCH; ++b) {
        int i = b * N + n;
        float e = E[i];
        float S = e + c[b];
        S = fminf(fmaxf(S, CLAMP_MIN_F), CLAMP_MAX_F);
        bool gt = S > t;
        float no = fmaxf(S - t, 0.0f);
        float ne;
        if (gt)           ne = no;
        else if (S == e)  ne = e - dc;
        else              ne = S;
        new_o[i] = no;
        new_e[i] = ne;
    }
}

// ---- R3 path (single chemT, device-scope atomics) for medium ws ----
__global__ void transpose_BN_to_NB(const float* __restrict__ in,
                                   float* __restrict__ out, int N) {
    int n = blockIdx.x * blockDim.x + threadIdx.x;
    if (n >= N) return;
    float v[BATCH];
    #pragma unroll
    for (int b = 0; b < BATCH; ++b) v[b] = in[b * N + n];
    float4* o = (float4*)&out[(size_t)n * BATCH];
    o[0] = make_float4(v[0], v[1], v[2], v[3]);
    o[1] = make_float4(v[4], v[5], v[6], v[7]);
}
__global__ void edge_scatter_eb(const int* __restrict__ src,
                                const int* __restrict__ dst,
                                const float* __restrict__ w,
                                const float* __restrict__ o_preT,
                                const float* __restrict__ E_T,
                                float* __restrict__ chemT,
                                int edges) {
    int t = blockIdx.x * blockDim.x + threadIdx.x;
    int e = t >> 3;
    int b = t & 7;
    if (e >= edges) return;
    int s = src[e]; int d = dst[e]; float we = w[e];
    float Oj = o_preT[(size_t)s * BATCH + b];
    float En = E_T[(size_t)d * BATCH + b];
    float diff = Oj - En;
    float sg = (diff > 0.0f) ? 1.0f : ((diff < 0.0f) ? -1.0f : 0.0f);
    atomicAdd(&chemT[(size_t)d * BATCH + b], Oj * we * sg);
}
__global__ void finalize_nb(const float* __restrict__ E,
                            const float* __restrict__ chemT,
                            const float* __restrict__ thr,
                            const float* __restrict__ decay,
                            float* __restrict__ new_o,
                            float* __restrict__ new_e, int N) {
    int n = blockIdx.x * blockDim.x + threadIdx.x;
    if (n >= N) return;
    const float4* cp = (const float4*)&chemT[(size_t)n * BATCH];
    float4 c0 = cp[0], c1 = cp[1];
    float c[BATCH] = {c0.x, c0.y, c0.z, c0.w, c1.x, c1.y, c1.z, c1.w};
    float t = thr[n];
    float dc = decay[n];
    #pragma unroll
    for (int b = 0; b < BATCH; ++b) {
        int i = b * N + n;
        float e = E[i];
        float S = fminf(fmaxf(e + c[b], CLAMP_MIN_F), CLAMP_MAX_F);
        bool gt = S > t;
        float no = fmaxf(S - t, 0.0f);
        float ne = gt ? no : ((S == e) ? (e - dc) : S);
        new_o[i] = no;
        new_e[i] = ne;
    }
}

extern "C" void kernel_launch(void* const* d_in, const int* in_sizes, int n_in,
                              void* d_out, int out_size, void* d_ws, size_t ws_size,
                              hipStream_t stream) {
    const float* chem_influence = (const float*)d_in[0];
    const float* E              = (const float*)d_in[1];
    const int*   src            = (const int*)d_in[3];
    const int*   dst            = (const int*)d_in[4];
    const float* w              = (const float*)d_in[5];
    const float* o_pre          = (const float*)d_in[6];
    const float* threshold      = (const float*)d_in[7];
    const float* decay          = (const float*)d_in[8];

    const int edges = in_sizes[3];
    const int BN    = in_sizes[0];   // B * N
    const int N     = in_sizes[7];   // threshold is (N,)

    float* new_o = (float*)d_out;
    float* new_e = (float*)d_out + BN;

    const int TB = 256;
    const size_t tableBytes = (size_t)BN * sizeof(float);
    int nblk = (N + TB - 1) / TB;
    long long ethreads = (long long)edges * BATCH;
    int gblk = (int)((ethreads + TB - 1) / TB);

    if (ws_size >= (size_t)(NREP + 2) * tableBytes) {
        // chemRep: NREP replicas of (N,B); then o_preT, E_T
        float* chemRep = (float*)d_ws;
        float* o_preT  = chemRep + (size_t)NREP * BN;
        float* E_T     = o_preT + BN;

        prep_kernel<<<nblk, TB, 0, stream>>>(chem_influence, o_pre, E,
                                             chemRep, o_preT, E_T, N, BN);
        edge_scatter_rep<<<gblk, TB, 0, stream>>>(src, dst, w, o_preT, E_T,
                                                  chemRep, edges, BN);
        finalize_rep<<<nblk, TB, 0, stream>>>(E, chemRep, threshold, decay,
                                              new_o, new_e, N, BN);
    } else if (ws_size >= 3 * tableBytes) {
        float* chemT  = (float*)d_ws;
        float* o_preT = chemT + BN;
        float* E_T    = o_preT + BN;
        transpose_BN_to_NB<<<nblk, TB, 0, stream>>>(chem_influence, chemT, N);
        transpose_BN_to_NB<<<nblk, TB, 0, stream>>>(o_pre, o_preT, N);
        transpose_BN_to_NB<<<nblk, TB, 0, stream>>>(E, E_T, N);
        edge_scatter_eb<<<gblk, TB, 0, stream>>>(src, dst, w, o_preT, E_T,
                                                 chemT, edges);
        finalize_nb<<<nblk, TB, 0, stream>>>(E, chemT, threshold, decay,
                                             new_o, new_e, N);
    }
}